// Round 5
// baseline (131.178 us; speedup 1.0000x reference)
//
#include <hip/hip_runtime.h>
#include <math.h>

#define N      512
#define RNUM   4
#define BNUM   2
#define NSLICE (RNUM * BNUM)
#define TILE   128               // (a,b) tile 128x128; 512 threads x (8a x 4b)
#define CT     32                // c-chunk per LDS stage
#define LSTRF  132               // f32 row stride (528 B)
#define CSPLIT 16                // c-split -> 2048 main blocks
#define NCOLB  8                 // colsum-role blocks (1 per slice, 512 threads)
#define SCALE  0.0625f           // (1/2 relu-split) * (1/8 weight/(R*B))

typedef _Float16 half2_t __attribute__((ext_vector_type(2)));

__device__ __forceinline__ half2_t u2h(unsigned int u) {
  return __builtin_bit_cast(half2_t, u);
}

__device__ __forceinline__ float sigmoidf_(float x) {
  return 1.0f / (1.0f + __expf(-x));
}

__device__ __forceinline__ unsigned packh2(float a, float b) {
  half2_t h = {(_Float16)a, (_Float16)b};
  return __builtin_bit_cast(unsigned, h);
}

__global__ void zero_out_kernel(float* out) { out[0] = 0.0f; }

// prep: one thread per (b,i,4xj): 64B contiguous logits load (4x float4),
// 16 sigmoids, per-plane 8B packed store (uint2 of 4 f16). P stays f16 (4MB).
__global__ __launch_bounds__(256) void prep_f16_kernel(const float* __restrict__ logits,
                                                       const int* __restrict__ masks,
                                                       _Float16* __restrict__ P,
                                                       float* __restrict__ out) {
  if (blockIdx.x == 0 && threadIdx.x == 0) out[0] = 0.0f;
  int t = blockIdx.x * 256 + threadIdx.x;      // 0 .. B*N*N/4 - 1
  int b = t >> 16;                              // / (N*N/4)
  int rem4 = t & (N * N / 4 - 1);
  int i = rem4 >> 7;                            // row
  int j4 = rem4 & 127;                          // j-group (j = 4*j4)
  const float4* Lp = ((const float4*)logits) + ((size_t)(b * N + i) * N + 4 * j4);
  float4 l0 = Lp[0], l1 = Lp[1], l2 = Lp[2], l3 = Lp[3];
  int4 mj = *(const int4*)(masks + b * N + 4 * j4);
  float mi = (masks[b * N + i] > 0) ? 1.0f : 0.0f;
  float m0 = mi * ((mj.x > 0) ? 1.0f : 0.0f);
  float m1 = mi * ((mj.y > 0) ? 1.0f : 0.0f);
  float m2 = mi * ((mj.z > 0) ? 1.0f : 0.0f);
  float m3 = mi * ((mj.w > 0) ? 1.0f : 0.0f);
  size_t off = (size_t)i * N + 4 * j4;
  _Float16* Pb = P + (size_t)b * RNUM * N * N + off;
  {
    uint2 v = {packh2(m0 * sigmoidf_(l0.x), m1 * sigmoidf_(l1.x)),
               packh2(m2 * sigmoidf_(l2.x), m3 * sigmoidf_(l3.x))};
    *(uint2*)(Pb + 0 * (size_t)N * N) = v;
  }
  {
    uint2 v = {packh2(m0 * sigmoidf_(l0.y), m1 * sigmoidf_(l1.y)),
               packh2(m2 * sigmoidf_(l2.y), m3 * sigmoidf_(l3.y))};
    *(uint2*)(Pb + 1 * (size_t)N * N) = v;
  }
  {
    uint2 v = {packh2(m0 * sigmoidf_(l0.z), m1 * sigmoidf_(l1.z)),
               packh2(m2 * sigmoidf_(l2.z), m3 * sigmoidf_(l3.z))};
    *(uint2*)(Pb + 2 * (size_t)N * N) = v;
  }
  {
    uint2 v = {packh2(m0 * sigmoidf_(l0.w), m1 * sigmoidf_(l1.w)),
               packh2(m2 * sigmoidf_(l2.w), m3 * sigmoidf_(l3.w))};
    *(uint2*)(Pb + 3 * (size_t)N * N) = v;
  }
}

// R13 journal. R12 (f32 math) regressed 60.9->77.9 from two counter-visible
// pathologies, NOT the f32 theory:
//  (1) genuine spill: VGPR=32 vs need ~56 at (512,8)/64-cap; WRITE_SIZE
//      64.5KB -> 5.4MB (scratch stores; reloads hit L2, invisible in FETCH).
//  (2) 4-way LDS read conflict (SQ_LDS_BANK_CONFLICT 0 -> 4.2M): consecutive-8
//      f32 a-read = float4 @ dword ta*8 -> banks {0,8,16,24}. The ORIGINAL
//      split 4+4 mapping (ta*4 and 64+ta*4) is 2-way = free for f32 — that is
//      why the old kernel used it (R2 f16 b128 was accidentally safe at 16B).
// Fixes, nothing else touched:
//  * __launch_bounds__(512,4): 128-reg cap, need ~56-70 -> no spill. <=64
//    regs => 8 waves/SIMD; 65+ => 4 waves/SIMD (R1: costs <=7%).
//  * a-cols split 4+4: a = a0+ta*4+{0..3} and a0+64+ta*4+{0..3};
//    two b128 LDS reads, 2-way alias (m136: free). b-read unchanged
//    (tbgq*4: 16-lane broadcast, 4 distinct banks, conflict-free).
// FALSIFIER: VGPR<=32 + MB-scale WRITE_SIZE again => compiler refuses
// residency under any budget => R14 wraps rab loads in asm volatile.
__global__ __launch_bounds__(512, 4) void work_f16_kernel(const _Float16* __restrict__ P,
                                                          float* __restrict__ out) {
  __shared__ __align__(16) float tA[CT][LSTRF];
  __shared__ __align__(16) float tB[CT][LSTRF];
  __shared__ float wsum[8];

  const int tid = threadIdx.x;
  const int bid = blockIdx.x;

  if (bid < NCOLB) {
    // ---- colsum role: Sum_c csum_c*(N-csum_c), one block per slice ----
    const int s = bid;
    const int c = tid;                      // 0..511
    const _Float16* col = P + (size_t)s * N * N + c;
    float sum = 0.0f;
#pragma unroll 16
    for (int a = 0; a < N; ++a) sum += (float)col[(size_t)a * N];
    float v = sum * ((float)N - sum);
    for (int off = 32; off > 0; off >>= 1) v += __shfl_down(v, off, 64);
    const int wid = tid >> 6;
    if ((tid & 63) == 0) wsum[wid] = v;
    __syncthreads();
    if (tid == 0) {
      float t = 0.0f;
#pragma unroll
      for (int w = 0; w < 8; ++w) t += wsum[w];
      atomicAdd(out, t * SCALE);
    }
    return;
  }

  // ---- main role: Sum |rab - a_c*b_c| in f32 ----
  const int m  = bid - NCOLB;
  const int bt = m & 3;
  const int at = (m >> 2) & 3;
  const int s  = (m >> 4) & 7;
  const int cz = m >> 7;                    // 0..CSPLIT-1
  const int a0 = at * TILE;
  const int b0 = bt * TILE;
  const int c0 = cz * CT;                   // one CT-chunk per block

  const int ta   = tid & 15;   // a cols: a0 + ta*4 + {0..3} and +64
  const int tbgq = tid >> 4;   // b cols: b0 + tbgq*4 + {0..3}  (0..31)

  const _Float16* Ph = P + (size_t)s * N * N;

  // staging: thread r=tid&127, oct=tid>>7 stages cols [oct*8,oct*8+8) of row r
  // for BOTH tiles, converting f16->f32. ds_writes: fixed (oct,k), lanes are
  // 64 consecutive r -> consecutive dwords -> 2-way bank alias (free).
  {
    const int r   = tid & 127;
    const int oct = tid >> 7;               // 0..3
    const _Float16* sa = Ph + (size_t)(a0 + r) * N + c0 + oct * 8;
    const _Float16* sb = Ph + (size_t)(b0 + r) * N + c0 + oct * 8;
    uint4 qa = *(const uint4*)sa;
    uint4 qb = *(const uint4*)sb;
    unsigned wa[4] = {qa.x, qa.y, qa.z, qa.w};
    unsigned wb[4] = {qb.x, qb.y, qb.z, qb.w};
#pragma unroll
    for (int k = 0; k < 4; ++k) {
      half2_t ha = u2h(wa[k]);
      half2_t hb = u2h(wb[k]);
      tA[oct * 8 + 2 * k    ][r] = (float)ha.x;
      tA[oct * 8 + 2 * k + 1][r] = (float)ha.y;
      tB[oct * 8 + 2 * k    ][r] = (float)hb.x;
      tB[oct * 8 + 2 * k + 1][r] = (float)hb.y;
    }
  }

  // rab tile: per x one dwordx2 (4 f16), unpack once to f32.
  // x -> a-row: a0 + ((x>>2)<<6) + ta*4 + (x&3)
  float rabf[8][4];
#pragma unroll
  for (int x = 0; x < 8; ++x) {
    int ga = a0 + ((x >> 2) << 6) + ta * 4 + (x & 3);
    uint2 q = *(const uint2*)(Ph + (size_t)ga * N + b0 + tbgq * 4);
    half2_t h0 = u2h(q.x);
    half2_t h1 = u2h(q.y);
    rabf[x][0] = (float)h0.x; rabf[x][1] = (float)h0.y;
    rabf[x][2] = (float)h1.x; rabf[x][3] = (float)h1.y;
  }

  float acc[8];
#pragma unroll
  for (int x = 0; x < 8; ++x) acc[x] = 0.0f;

  __syncthreads();

#pragma unroll 2
  for (int c = 0; c < CT; ++c) {
    float4 a0v = *(const float4*)&tA[c][ta * 4];        // banks ta*4%32: 2-way
    float4 a1v = *(const float4*)&tA[c][64 + ta * 4];   // 2-way
    float4 b0v = *(const float4*)&tB[c][tbgq * 4];      // broadcast/4-bank
    float av[8] = {a0v.x, a0v.y, a0v.z, a0v.w, a1v.x, a1v.y, a1v.z, a1v.w};
    float bv[4] = {b0v.x, b0v.y, b0v.z, b0v.w};
#pragma unroll
    for (int x = 0; x < 8; ++x) {
#pragma unroll
      for (int y = 0; y < 4; ++y)
        acc[x] += fabsf(fmaf(-av[x], bv[y], rabf[x][y]));   // v_fma + v_add(|.|)
    }
  }

  float tsum = 0.0f;
#pragma unroll
  for (int x = 0; x < 8; ++x) tsum += acc[x];

  for (int off = 32; off > 0; off >>= 1) tsum += __shfl_down(tsum, off, 64);

  const int wid = tid >> 6;
  if ((tid & 63) == 0) wsum[wid] = tsum;
  __syncthreads();
  if (tid == 0) {
    float t = 0.0f;
#pragma unroll
    for (int w = 0; w < 8; ++w) t += wsum[w];
    atomicAdd(out, t * SCALE);
  }
}

// ---------------- f32 fallback (no workspace): R4 structure ----------------
#define FCT    64
#define FSTR   132
#define FCSPL  4
#define FNCOLB 16

__global__ __launch_bounds__(256, 2) void work_f32_fallback(const float* __restrict__ logits,
                                                            const int* __restrict__ masks,
                                                            float* __restrict__ out) {
  __shared__ __align__(16) float tA[FCT][FSTR];
  __shared__ __align__(16) float tB[FCT][FSTR];
  __shared__ float wsum[4];

  const int tid = threadIdx.x;
  const int bid = blockIdx.x;

  if (bid < FNCOLB) {
    const int s    = bid >> 1;
    const int half = bid & 1;
    const int c    = half * 256 + tid;
    const int bb   = s >> 2;
    const int r    = s & 3;
    const int* mrow = masks + bb * N;
    float mc = (mrow[c] > 0) ? 1.0f : 0.0f;
    float sum = 0.0f;
#pragma unroll 4
    for (int a = 0; a < N; ++a) {
      float ma = (mrow[a] > 0) ? 1.0f : 0.0f;
      size_t idx = ((size_t)(bb * N + a) * N + c) * RNUM + r;
      sum += sigmoidf_(logits[idx]) * ma * mc;
    }
    float v = sum * ((float)N - sum);
    for (int off = 32; off > 0; off >>= 1) v += __shfl_down(v, off, 64);
    const int wid = tid >> 6;
    if ((tid & 63) == 0) wsum[wid] = v;
    __syncthreads();
    if (tid == 0)
      atomicAdd(out, (wsum[0] + wsum[1] + wsum[2] + wsum[3]) * SCALE);
    return;
  }

  const int m  = bid - FNCOLB;
  const int bt = m & 3;
  const int at = (m >> 2) & 3;
  const int s  = (m >> 4) & 7;
  const int cz = m >> 7;
  const int a0 = at * TILE;
  const int b0 = bt * TILE;
  const int bb = s >> 2;
  const int r  = s & 3;
  const int cbeg = cz * (N / FCSPL);
  const int cend = cbeg + (N / FCSPL);

  const int ta = tid & 15;
  const int tb = tid >> 4;
  const int* mrow = masks + bb * N;

  float rab[8][8];
#pragma unroll
  for (int x = 0; x < 8; ++x) {
    int ra = a0 + ((x >> 2) << 6) + ta * 4 + (x & 3);
    float ma = (mrow[ra] > 0) ? 1.0f : 0.0f;
#pragma unroll
    for (int y = 0; y < 8; ++y) {
      int cb = b0 + ((y >> 2) << 6) + tb * 4 + (y & 3);
      float mb = (mrow[cb] > 0) ? 1.0f : 0.0f;
      size_t idx = ((size_t)(bb * N + ra) * N + cb) * RNUM + r;
      rab[x][y] = sigmoidf_(logits[idx]) * ma * mb;
    }
  }

  float acc[8][2];
#pragma unroll
  for (int x = 0; x < 8; ++x) { acc[x][0] = 0.0f; acc[x][1] = 0.0f; }

  for (int c0 = cbeg; c0 < cend; c0 += FCT) {
    __syncthreads();
#pragma unroll
    for (int it = 0; it < 32; ++it) {
      int e = it * 256 + tid;
      int c = e & 63;
      int i = e >> 6;
      int pc = ((((i >> 2) ^ ((c >> 2) & 31)) & 31) << 2) | (i & 3);
      float mc = (mrow[c0 + c] > 0) ? 1.0f : 0.0f;
      {
        float mi = (mrow[a0 + i] > 0) ? 1.0f : 0.0f;
        size_t idx = ((size_t)(bb * N + a0 + i) * N + (c0 + c)) * RNUM + r;
        tA[c][pc] = sigmoidf_(logits[idx]) * mi * mc;
      }
      {
        float mi = (mrow[b0 + i] > 0) ? 1.0f : 0.0f;
        size_t idx = ((size_t)(bb * N + b0 + i) * N + (c0 + c)) * RNUM + r;
        tB[c][pc] = sigmoidf_(logits[idx]) * mi * mc;
      }
    }
    __syncthreads();

#pragma unroll 2
    for (int cg = 0; cg < FCT / 4; ++cg) {
      const float* pa = &tA[cg * 4][((ta ^ cg) & 31) << 2];
      const float* pb = &tB[cg * 4][((tb ^ cg) & 31) << 2];
#pragma unroll
      for (int dc = 0; dc < 4; ++dc) {
        float4 a0v = *(const float4*)(pa + dc * FSTR);
        float4 a1v = *(const float4*)(pa + dc * FSTR + 64);
        float4 b0v = *(const float4*)(pb + dc * FSTR);
        float4 b1v = *(const float4*)(pb + dc * FSTR + 64);
        float avv[8] = {a0v.x, a0v.y, a0v.z, a0v.w, a1v.x, a1v.y, a1v.z, a1v.w};
        float bvv[8] = {b0v.x, b0v.y, b0v.z, b0v.w, b1v.x, b1v.y, b1v.z, b1v.w};
#pragma unroll
        for (int x = 0; x < 8; ++x) {
#pragma unroll
          for (int y = 0; y < 4; ++y)
            acc[x][0] += fabsf(fmaf(-avv[x], bvv[y], rab[x][y]));
#pragma unroll
          for (int y = 4; y < 8; ++y)
            acc[x][1] += fabsf(fmaf(-avv[x], bvv[y], rab[x][y]));
        }
      }
    }
  }

  float tsum = 0.0f;
#pragma unroll
  for (int x = 0; x < 8; ++x) tsum += acc[x][0] + acc[x][1];
  for (int off = 32; off > 0; off >>= 1) tsum += __shfl_down(tsum, off, 64);
  const int wid = tid >> 6;
  if ((tid & 63) == 0) wsum[wid] = tsum;
  __syncthreads();
  if (tid == 0)
    atomicAdd(out, (wsum[0] + wsum[1] + wsum[2] + wsum[3]) * SCALE);
}

extern "C" void kernel_launch(void* const* d_in, const int* in_sizes, int n_in,
                              void* d_out, int out_size, void* d_ws, size_t ws_size,
                              hipStream_t stream) {
  const float* logits = (const float*)d_in[0];
  const int*   masks  = (const int*)d_in[1];
  float*       out    = (float*)d_out;

  const size_t P_BYTES = (size_t)NSLICE * N * N * sizeof(_Float16);  // 4 MB

  if (ws_size >= P_BYTES) {
    _Float16* P = (_Float16*)d_ws;
    prep_f16_kernel<<<(BNUM * N * N / 4) / 256, 256, 0, stream>>>(logits, masks, P, out);
    const int nblocks = NCOLB + 4 * 4 * NSLICE * CSPLIT;  // 8 + 2048
    work_f16_kernel<<<nblocks, 512, 0, stream>>>(P, out);
  } else {
    zero_out_kernel<<<1, 1, 0, stream>>>(out);
    const int nblocks = FNCOLB + 4 * 4 * NSLICE * FCSPL;  // 16 + 512
    work_f32_fallback<<<nblocks, 256, 0, stream>>>(logits, masks, out);
  }
}

// Round 6
// 115.041 us; speedup vs baseline: 1.1403x; 1.1403x over previous
//
#include <hip/hip_runtime.h>
#include <math.h>

#define N      512
#define RNUM   4
#define BNUM   2
#define NSLICE (RNUM * BNUM)
#define TILE   128               // (a,b) tile 128x128, 256 threads x (8x8)
#define CT     32                // c-chunk per LDS buffer
#define LSTR   136               // f16 row stride (272 B) - bank-verified
#define CSPLIT 8                 // c-split -> 1024 main blocks, 2 chunks each
#define NCOLB  16                // colsum-role blocks (8 slices x 2 halves)
#define SCALE  0.0625f           // (1/2 relu-split) * (1/8 weight/(R*B))

typedef _Float16 half2_t __attribute__((ext_vector_type(2)));

__device__ __forceinline__ unsigned int h2u(half2_t h) {
  return __builtin_bit_cast(unsigned int, h);
}
__device__ __forceinline__ half2_t u2h(unsigned int u) {
  return __builtin_bit_cast(half2_t, u);
}

#if __has_builtin(__builtin_amdgcn_fdot2)
__device__ __forceinline__ float fdot2_(half2_t a, half2_t b, float c) {
  return __builtin_amdgcn_fdot2(a, b, c, false);
}
#else
__device__ __forceinline__ float fdot2_(half2_t a, half2_t b, float c) {
  return c + (float)a.x * (float)b.x + (float)a.y * (float)b.y;
}
#endif

__device__ __forceinline__ float sigmoidf_(float x) {
  return 1.0f / (1.0f + __expf(-x));
}

__device__ __forceinline__ unsigned packh2(float a, float b) {
  half2_t h = {(_Float16)a, (_Float16)b};
  return h2u(h);
}

__global__ void zero_out_kernel(float* out) { out[0] = 0.0f; }

// prep: one thread per (b,i,4xj): 64B contiguous logits load (4x float4),
// 16 sigmoids, per-plane 8B packed store (uint2 of 4 f16). P stays f16 (4MB).
__global__ __launch_bounds__(256) void prep_f16_kernel(const float* __restrict__ logits,
                                                       const int* __restrict__ masks,
                                                       _Float16* __restrict__ P,
                                                       float* __restrict__ out) {
  if (blockIdx.x == 0 && threadIdx.x == 0) out[0] = 0.0f;
  int t = blockIdx.x * 256 + threadIdx.x;      // 0 .. B*N*N/4 - 1
  int b = t >> 16;                              // / (N*N/4)
  int rem4 = t & (N * N / 4 - 1);
  int i = rem4 >> 7;                            // row
  int j4 = rem4 & 127;                          // j-group (j = 4*j4)
  const float4* Lp = ((const float4*)logits) + ((size_t)(b * N + i) * N + 4 * j4);
  float4 l0 = Lp[0], l1 = Lp[1], l2 = Lp[2], l3 = Lp[3];
  int4 mj = *(const int4*)(masks + b * N + 4 * j4);
  float mi = (masks[b * N + i] > 0) ? 1.0f : 0.0f;
  float m0 = mi * ((mj.x > 0) ? 1.0f : 0.0f);
  float m1 = mi * ((mj.y > 0) ? 1.0f : 0.0f);
  float m2 = mi * ((mj.z > 0) ? 1.0f : 0.0f);
  float m3 = mi * ((mj.w > 0) ? 1.0f : 0.0f);
  size_t off = (size_t)i * N + 4 * j4;
  _Float16* Pb = P + (size_t)b * RNUM * N * N + off;
  {
    uint2 v = {packh2(m0 * sigmoidf_(l0.x), m1 * sigmoidf_(l1.x)),
               packh2(m2 * sigmoidf_(l2.x), m3 * sigmoidf_(l3.x))};
    *(uint2*)(Pb + 0 * (size_t)N * N) = v;
  }
  {
    uint2 v = {packh2(m0 * sigmoidf_(l0.y), m1 * sigmoidf_(l1.y)),
               packh2(m2 * sigmoidf_(l2.y), m3 * sigmoidf_(l3.y))};
    *(uint2*)(Pb + 1 * (size_t)N * N) = v;
  }
  {
    uint2 v = {packh2(m0 * sigmoidf_(l0.z), m1 * sigmoidf_(l1.z)),
               packh2(m2 * sigmoidf_(l2.z), m3 * sigmoidf_(l3.z))};
    *(uint2*)(Pb + 2 * (size_t)N * N) = v;
  }
  {
    uint2 v = {packh2(m0 * sigmoidf_(l0.w), m1 * sigmoidf_(l1.w)),
               packh2(m2 * sigmoidf_(l2.w), m3 * sigmoidf_(l3.w))};
    *(uint2*)(Pb + 3 * (size_t)N * N) = v;
  }
}

// R14 journal — MODEL CLOSED: 6 configs (R8-R13) all fit wall-busy =
// wave_insts x ~4 cyc (R13 f32: 4.03; R8-R11 f16: 3.9). Every VALU inst
// issues at 4 cyc/wave64; packed VOP3P carries 2 elems (m07's 103 TF = 66%
// of the 157 TF that v_pk_fma_f32@4cyc gives — the 2-cyc reading was wrong).
// => f32 scalar (8 cyc/elem) can never beat packed f16 (3 cyc/elem);
// => f16 inner {pk_fma, and, dot2} = 3 VOP3P / 2 elems is the ISA floor
//    (abs/relu unfusable; pk_max/dot-tricks all >=3): busy floor ~42us.
// Remaining lever: the ~17us idle (59.4 wall @ 71% busy-frac; best observed
// busy-frac 78% in R12). This round: R10(=best, 59.4us) + dbuf 2-chunking:
//  * CSPLIT=8, 1024 blocks, each block does chunks c0, c0+32 with
//    double-buffered LDS (2x17.4 = 34.8KB, 4 blocks/CU):
//    stage(buf0); rab; bar; stage(buf1); compute(buf0); bar; compute(buf1)
//    - chunk1 staging latency hides under chunk0 compute (disjoint buffers,
//      no barrier between), rab/tail amortize 2x, t=0 burst halves.
//  * inner loop / staging / colsum / prep verbatim from R10 (measured:
//    0 bank conflicts, VGPR 32, best wall).
// FALSIFIER: work >= 59us => idle is wave-slot-structural; busy already at
// ISA floor => roofline next round.
__global__ __launch_bounds__(256, 8) void work_f16_kernel(const _Float16* __restrict__ P,
                                                          float* __restrict__ out) {
  __shared__ __align__(16) _Float16 tA[2][CT][LSTR];
  __shared__ __align__(16) _Float16 tB[2][CT][LSTR];
  __shared__ float wsum[4];

  const int tid = threadIdx.x;
  const int bid = blockIdx.x;

  if (bid < NCOLB) {
    // ---- colsum role: Sum_c csum_c*(N-csum_c) (factorized linear half) ----
    const int s    = bid >> 1;
    const int half = bid & 1;
    const int c    = half * 256 + tid;
    const _Float16* col = P + (size_t)s * N * N + c;
    float sum = 0.0f;
#pragma unroll 16
    for (int a = 0; a < N; ++a) sum += (float)col[(size_t)a * N];
    float v = sum * ((float)N - sum);
    for (int off = 32; off > 0; off >>= 1) v += __shfl_down(v, off, 64);
    const int wid = tid >> 6;
    if ((tid & 63) == 0) wsum[wid] = v;
    __syncthreads();
    if (tid == 0)
      atomicAdd(out, (wsum[0] + wsum[1] + wsum[2] + wsum[3]) * SCALE);
    return;
  }

  // ---- main role: Sum |rab - a_c*b_c| (abs half), packed f16 ----
  const int m  = bid - NCOLB;
  const int bt = m & 3;
  const int at = (m >> 2) & 3;
  const int s  = (m >> 4) & 7;
  const int cz = m >> 7;                    // 0..CSPLIT-1
  const int a0 = at * TILE;
  const int b0 = bt * TILE;
  const int c0 = cz * (2 * CT);             // two CT-chunks per block

  const int ta = tid & 15;    // a cols: a0 + ta*8 + {0..7}
  const int tb = tid >> 4;    // b cols: b0 + tb*8 + {0..7}

  const _Float16* Ph = P + (size_t)s * N * N;

  // staging params (R10-verbatim pattern): thread transposes a ROW-PAIR
  // (2 rows) x 16 c's, packing {row0[c],row1[c]} u32 into LDS column pair.
  // Writes: 64 consecutive dwords per wave = 2-way bank alias = free.
  const int su   = tid & 127;
  const int sh   = tid >> 7;
  const int sisB = su >> 6;
  const int sp   = su & 63;
  const int srow = (sisB ? b0 : a0) + 2 * sp;

#define STAGE_CHUNK(cc, buf)                                                   \
  {                                                                            \
    const _Float16* s0row = Ph + (size_t)srow * N + (cc) + sh * 16;            \
    const _Float16* s1row = s0row + N;                                         \
    _Float16* dst = sisB ? &tB[buf][sh * 16][2 * sp] : &tA[buf][sh * 16][2 * sp]; \
    uint4 q0 = ((const uint4*)s0row)[0];                                       \
    uint4 q1 = ((const uint4*)s0row)[1];                                       \
    uint4 r0v = ((const uint4*)s1row)[0];                                      \
    uint4 r1v = ((const uint4*)s1row)[1];                                      \
    unsigned int w0[8] = {q0.x, q0.y, q0.z, q0.w, q1.x, q1.y, q1.z, q1.w};     \
    unsigned int w1[8] = {r0v.x, r0v.y, r0v.z, r0v.w, r1v.x, r1v.y, r1v.z, r1v.w}; \
    _Pragma("unroll")                                                          \
    for (int k = 0; k < 8; ++k) {                                              \
      unsigned int lo = (w1[k] << 16) | (w0[k] & 0xFFFFu);                     \
      unsigned int hi = (w1[k] & 0xFFFF0000u) | (w0[k] >> 16);                 \
      *(unsigned int*)(dst + (size_t)(2 * k) * LSTR)     = lo;                 \
      *(unsigned int*)(dst + (size_t)(2 * k + 1) * LSTR) = hi;                 \
    }                                                                          \
  }

  // stage chunk 0 into buf 0
  STAGE_CHUNK(c0, 0)

  // rab tile: 8 consecutive b's per a -> one dwordx4 per x (R10-verbatim).
  half2_t rab2[8][4];
#pragma unroll
  for (int x = 0; x < 8; ++x) {
    int ga = a0 + ta * 8 + x;
    uint4 q = *(const uint4*)(Ph + (size_t)ga * N + b0 + tb * 8);
    rab2[x][0] = u2h(q.x); rab2[x][1] = u2h(q.y);
    rab2[x][2] = u2h(q.z); rab2[x][3] = u2h(q.w);
  }

  float acc[8];
#pragma unroll
  for (int x = 0; x < 8; ++x) acc[x] = 0.0f;

  const half2_t kOne = {(_Float16)1.0f, (_Float16)1.0f};

  __syncthreads();

  // stage chunk 1 into buf 1 — no barrier needed: buf1 is not read until
  // after the next __syncthreads(); global latency hides under compute(buf0).
  STAGE_CHUNK(c0 + CT, 1)

#define COMPUTE_CHUNK(buf)                                                     \
  _Pragma("unroll 4")                                                          \
  for (int c = 0; c < CT; ++c) {                                               \
    uint4 ua = *(const uint4*)&tA[buf][c][ta * 8];                             \
    uint4 ub = *(const uint4*)&tB[buf][c][tb * 8];                             \
    half2_t av[4] = {u2h(ua.x), u2h(ua.y), u2h(ua.z), u2h(ua.w)};              \
    half2_t bv[4] = {u2h(ub.x), u2h(ub.y), u2h(ub.z), u2h(ub.w)};              \
    _Pragma("unroll")                                                          \
    for (int x = 0; x < 8; ++x) {                                              \
      _Float16 as = (x & 1) ? av[x >> 1].y : av[x >> 1].x;                     \
      half2_t asp = {as, as};                                                  \
      float a_ = acc[x];                                                       \
      _Pragma("unroll")                                                        \
      for (int yp = 0; yp < 4; ++yp) {                                         \
        half2_t t2 = rab2[x][yp] - asp * bv[yp];     /* v_pk_fma_f16 (neg) */  \
        half2_t p2 = u2h(h2u(t2) & 0x7FFF7FFFu);     /* packed |t| */          \
        a_ = fdot2_(p2, kOne, a_);                   /* f32 accumulate */      \
      }                                                                        \
      acc[x] = a_;                                                             \
    }                                                                          \
  }

  COMPUTE_CHUNK(0)

  __syncthreads();

  COMPUTE_CHUNK(1)

  float tsum = 0.0f;
#pragma unroll
  for (int x = 0; x < 8; ++x) tsum += acc[x];

  for (int off = 32; off > 0; off >>= 1) tsum += __shfl_down(tsum, off, 64);

  const int wid = tid >> 6;
  if ((tid & 63) == 0) wsum[wid] = tsum;
  __syncthreads();
  if (tid == 0)
    atomicAdd(out, (wsum[0] + wsum[1] + wsum[2] + wsum[3]) * SCALE);

#undef STAGE_CHUNK
#undef COMPUTE_CHUNK
}

// ---------------- f32 fallback (no workspace): R4 structure ----------------
#define FCT    64
#define FSTR   132
#define FCSPL  4
#define FNCOLB 16

__global__ __launch_bounds__(256, 2) void work_f32_fallback(const float* __restrict__ logits,
                                                            const int* __restrict__ masks,
                                                            float* __restrict__ out) {
  __shared__ __align__(16) float tA[FCT][FSTR];
  __shared__ __align__(16) float tB[FCT][FSTR];
  __shared__ float wsum[4];

  const int tid = threadIdx.x;
  const int bid = blockIdx.x;

  if (bid < FNCOLB) {
    const int s    = bid >> 1;
    const int half = bid & 1;
    const int c    = half * 256 + tid;
    const int bb   = s >> 2;
    const int r    = s & 3;
    const int* mrow = masks + bb * N;
    float mc = (mrow[c] > 0) ? 1.0f : 0.0f;
    float sum = 0.0f;
#pragma unroll 4
    for (int a = 0; a < N; ++a) {
      float ma = (mrow[a] > 0) ? 1.0f : 0.0f;
      size_t idx = ((size_t)(bb * N + a) * N + c) * RNUM + r;
      sum += sigmoidf_(logits[idx]) * ma * mc;
    }
    float v = sum * ((float)N - sum);
    for (int off = 32; off > 0; off >>= 1) v += __shfl_down(v, off, 64);
    const int wid = tid >> 6;
    if ((tid & 63) == 0) wsum[wid] = v;
    __syncthreads();
    if (tid == 0)
      atomicAdd(out, (wsum[0] + wsum[1] + wsum[2] + wsum[3]) * SCALE);
    return;
  }

  const int m  = bid - FNCOLB;
  const int bt = m & 3;
  const int at = (m >> 2) & 3;
  const int s  = (m >> 4) & 7;
  const int cz = m >> 7;
  const int a0 = at * TILE;
  const int b0 = bt * TILE;
  const int bb = s >> 2;
  const int r  = s & 3;
  const int cbeg = cz * (N / FCSPL);
  const int cend = cbeg + (N / FCSPL);

  const int ta = tid & 15;
  const int tb = tid >> 4;
  const int* mrow = masks + bb * N;

  float rab[8][8];
#pragma unroll
  for (int x = 0; x < 8; ++x) {
    int ra = a0 + ((x >> 2) << 6) + ta * 4 + (x & 3);
    float ma = (mrow[ra] > 0) ? 1.0f : 0.0f;
#pragma unroll
    for (int y = 0; y < 8; ++y) {
      int cb = b0 + ((y >> 2) << 6) + tb * 4 + (y & 3);
      float mb = (mrow[cb] > 0) ? 1.0f : 0.0f;
      size_t idx = ((size_t)(bb * N + ra) * N + cb) * RNUM + r;
      rab[x][y] = sigmoidf_(logits[idx]) * ma * mb;
    }
  }

  float acc[8][2];
#pragma unroll
  for (int x = 0; x < 8; ++x) { acc[x][0] = 0.0f; acc[x][1] = 0.0f; }

  for (int c0 = cbeg; c0 < cend; c0 += FCT) {
    __syncthreads();
#pragma unroll
    for (int it = 0; it < 32; ++it) {
      int e = it * 256 + tid;
      int c = e & 63;
      int i = e >> 6;
      int pc = ((((i >> 2) ^ ((c >> 2) & 31)) & 31) << 2) | (i & 3);
      float mc = (mrow[c0 + c] > 0) ? 1.0f : 0.0f;
      {
        float mi = (mrow[a0 + i] > 0) ? 1.0f : 0.0f;
        size_t idx = ((size_t)(bb * N + a0 + i) * N + (c0 + c)) * RNUM + r;
        tA[c][pc] = sigmoidf_(logits[idx]) * mi * mc;
      }
      {
        float mi = (mrow[b0 + i] > 0) ? 1.0f : 0.0f;
        size_t idx = ((size_t)(bb * N + b0 + i) * N + (c0 + c)) * RNUM + r;
        tB[c][pc] = sigmoidf_(logits[idx]) * mi * mc;
      }
    }
    __syncthreads();

#pragma unroll 2
    for (int cg = 0; cg < FCT / 4; ++cg) {
      const float* pa = &tA[cg * 4][((ta ^ cg) & 31) << 2];
      const float* pb = &tB[cg * 4][((tb ^ cg) & 31) << 2];
#pragma unroll
      for (int dc = 0; dc < 4; ++dc) {
        float4 a0v = *(const float4*)(pa + dc * FSTR);
        float4 a1v = *(const float4*)(pa + dc * FSTR + 64);
        float4 b0v = *(const float4*)(pb + dc * FSTR);
        float4 b1v = *(const float4*)(pb + dc * FSTR + 64);
        float avv[8] = {a0v.x, a0v.y, a0v.z, a0v.w, a1v.x, a1v.y, a1v.z, a1v.w};
        float bvv[8] = {b0v.x, b0v.y, b0v.z, b0v.w, b1v.x, b1v.y, b1v.z, b1v.w};
#pragma unroll
        for (int x = 0; x < 8; ++x) {
#pragma unroll
          for (int y = 0; y < 4; ++y)
            acc[x][0] += fabsf(fmaf(-avv[x], bvv[y], rab[x][y]));
#pragma unroll
          for (int y = 4; y < 8; ++y)
            acc[x][1] += fabsf(fmaf(-avv[x], bvv[y], rab[x][y]));
        }
      }
    }
  }

  float tsum = 0.0f;
#pragma unroll
  for (int x = 0; x < 8; ++x) tsum += acc[x][0] + acc[x][1];
  for (int off = 32; off > 0; off >>= 1) tsum += __shfl_down(tsum, off, 64);
  const int wid = tid >> 6;
  if ((tid & 63) == 0) wsum[wid] = tsum;
  __syncthreads();
  if (tid == 0)
    atomicAdd(out, (wsum[0] + wsum[1] + wsum[2] + wsum[3]) * SCALE);
}

extern "C" void kernel_launch(void* const* d_in, const int* in_sizes, int n_in,
                              void* d_out, int out_size, void* d_ws, size_t ws_size,
                              hipStream_t stream) {
  const float* logits = (const float*)d_in[0];
  const int*   masks  = (const int*)d_in[1];
  float*       out    = (float*)d_out;

  const size_t P_BYTES = (size_t)NSLICE * N * N * sizeof(_Float16);  // 4 MB

  if (ws_size >= P_BYTES) {
    _Float16* P = (_Float16*)d_ws;
    prep_f16_kernel<<<(BNUM * N * N / 4) / 256, 256, 0, stream>>>(logits, masks, P, out);
    const int nblocks = NCOLB + 4 * 4 * NSLICE * CSPLIT;  // 16 + 1024
    work_f16_kernel<<<nblocks, 256, 0, stream>>>(P, out);
  } else {
    zero_out_kernel<<<1, 1, 0, stream>>>(out);
    const int nblocks = FNCOLB + 4 * 4 * NSLICE * FCSPL;  // 16 + 512
    work_f32_fallback<<<nblocks, 256, 0, stream>>>(logits, masks, out);
  }
}

// Round 7
// 113.533 us; speedup vs baseline: 1.1554x; 1.0133x over previous
//
#include <hip/hip_runtime.h>
#include <math.h>

#define N      512
#define RNUM   4
#define BNUM   2
#define NSLICE (RNUM * BNUM)
#define TILE   128               // (a,b) tile 128x128, 256 threads x (8x8)
#define CT     32                // c-chunk per LDS stage
#define LSTR   136               // f16 row stride (272 B) - bank-verified
#define CSPLIT 16                // c-split -> 2048 main blocks (~8/CU)
#define NCOLB  16                // colsum-role blocks (8 slices x 2 halves)
#define SCALE  0.0625f           // (1/2 relu-split) * (1/8 weight/(R*B))

typedef _Float16 half2_t __attribute__((ext_vector_type(2)));

__device__ __forceinline__ unsigned int h2u(half2_t h) {
  return __builtin_bit_cast(unsigned int, h);
}
__device__ __forceinline__ half2_t u2h(unsigned int u) {
  return __builtin_bit_cast(half2_t, u);
}

#if __has_builtin(__builtin_amdgcn_fdot2)
__device__ __forceinline__ float fdot2_(half2_t a, half2_t b, float c) {
  return __builtin_amdgcn_fdot2(a, b, c, false);
}
#else
__device__ __forceinline__ float fdot2_(half2_t a, half2_t b, float c) {
  return c + (float)a.x * (float)b.x + (float)a.y * (float)b.y;
}
#endif

__device__ __forceinline__ float sigmoidf_(float x) {
  return 1.0f / (1.0f + __expf(-x));
}

__device__ __forceinline__ unsigned packh2(float a, float b) {
  half2_t h = {(_Float16)a, (_Float16)b};
  return h2u(h);
}

__global__ void zero_out_kernel(float* out) { out[0] = 0.0f; }

// prep: one thread per (b,i,4xj): 64B contiguous logits load (4x float4),
// 16 sigmoids, per-plane 8B packed store (uint2 of 4 f16). P stays f16 (4MB).
__global__ __launch_bounds__(256) void prep_f16_kernel(const float* __restrict__ logits,
                                                       const int* __restrict__ masks,
                                                       _Float16* __restrict__ P,
                                                       float* __restrict__ out) {
  if (blockIdx.x == 0 && threadIdx.x == 0) out[0] = 0.0f;
  int t = blockIdx.x * 256 + threadIdx.x;      // 0 .. B*N*N/4 - 1
  int b = t >> 16;                              // / (N*N/4)
  int rem4 = t & (N * N / 4 - 1);
  int i = rem4 >> 7;                            // row
  int j4 = rem4 & 127;                          // j-group (j = 4*j4)
  const float4* Lp = ((const float4*)logits) + ((size_t)(b * N + i) * N + 4 * j4);
  float4 l0 = Lp[0], l1 = Lp[1], l2 = Lp[2], l3 = Lp[3];
  int4 mj = *(const int4*)(masks + b * N + 4 * j4);
  float mi = (masks[b * N + i] > 0) ? 1.0f : 0.0f;
  float m0 = mi * ((mj.x > 0) ? 1.0f : 0.0f);
  float m1 = mi * ((mj.y > 0) ? 1.0f : 0.0f);
  float m2 = mi * ((mj.z > 0) ? 1.0f : 0.0f);
  float m3 = mi * ((mj.w > 0) ? 1.0f : 0.0f);
  size_t off = (size_t)i * N + 4 * j4;
  _Float16* Pb = P + (size_t)b * RNUM * N * N + off;
  {
    uint2 v = {packh2(m0 * sigmoidf_(l0.x), m1 * sigmoidf_(l1.x)),
               packh2(m2 * sigmoidf_(l2.x), m3 * sigmoidf_(l3.x))};
    *(uint2*)(Pb + 0 * (size_t)N * N) = v;
  }
  {
    uint2 v = {packh2(m0 * sigmoidf_(l0.y), m1 * sigmoidf_(l1.y)),
               packh2(m2 * sigmoidf_(l2.y), m3 * sigmoidf_(l3.y))};
    *(uint2*)(Pb + 1 * (size_t)N * N) = v;
  }
  {
    uint2 v = {packh2(m0 * sigmoidf_(l0.z), m1 * sigmoidf_(l1.z)),
               packh2(m2 * sigmoidf_(l2.z), m3 * sigmoidf_(l3.z))};
    *(uint2*)(Pb + 2 * (size_t)N * N) = v;
  }
  {
    uint2 v = {packh2(m0 * sigmoidf_(l0.w), m1 * sigmoidf_(l1.w)),
               packh2(m2 * sigmoidf_(l2.w), m3 * sigmoidf_(l3.w))};
    *(uint2*)(Pb + 3 * (size_t)N * N) = v;
  }
}

// R15 journal. Root-cause candidate for the stuck ~60us finally identified:
// VGPR_Count=32 across R8/R10/R11 CANNOT hold rab2 (32 regs) + acc(8) + tiles
// -> compiler REMATERIALIZES the rab tile from memory inside the c-loop
// (P=4MB is L2-resident: re-reads are L2 hits, invisible in FETCH_SIZE,
// ~8 hidden VMEM/c-iter = +~1000 cyc/wave = the whole 40% wall-over-floor
// gap; also explains occupancy/inst-count invariance of R8-R14 results).
// R9/R14's higher-VGPR builds were confounded (geometry change / vmcnt bug).
// This round, on the best kernel (R10 geometry, inner verbatim):
//  * ANTI-REMAT PIN: route all 32 rab words through asm volatile("":"+v")
//    after load -> provenance opaque -> compiler must keep them in VGPRs.
//  * LOAD ORDER: issue staging loads AND all 8 rab dwordx4 BEFORE the first
//    ds_write, so writes wait at vmcnt(8) with rab still in flight (R10
//    serialized two full latency chains: stage loads -> writes -> rab loads).
//  * __launch_bounds__(256,4): 128-reg budget for the pins.
// PREDICTION: VGPR 32 -> 64-80 (primary tell), WRITE_SIZE stays ~64KB,
// work 59.4 -> 48-53us. If VGPR jumps but wall stays ~60: remat theory dead,
// wall is structural, declare ceiling (busy floor 41us + fixed ~54us rest).
__global__ __launch_bounds__(256, 4) void work_f16_kernel(const _Float16* __restrict__ P,
                                                          float* __restrict__ out) {
  __shared__ __align__(16) _Float16 tA[CT][LSTR];
  __shared__ __align__(16) _Float16 tB[CT][LSTR];
  __shared__ float wsum[4];

  const int tid = threadIdx.x;
  const int bid = blockIdx.x;

  if (bid < NCOLB) {
    // ---- colsum role: Sum_c csum_c*(N-csum_c) (factorized linear half) ----
    const int s    = bid >> 1;
    const int half = bid & 1;
    const int c    = half * 256 + tid;
    const _Float16* col = P + (size_t)s * N * N + c;
    float sum = 0.0f;
#pragma unroll 16
    for (int a = 0; a < N; ++a) sum += (float)col[(size_t)a * N];
    float v = sum * ((float)N - sum);
    for (int off = 32; off > 0; off >>= 1) v += __shfl_down(v, off, 64);
    const int wid = tid >> 6;
    if ((tid & 63) == 0) wsum[wid] = v;
    __syncthreads();
    if (tid == 0)
      atomicAdd(out, (wsum[0] + wsum[1] + wsum[2] + wsum[3]) * SCALE);
    return;
  }

  // ---- main role: Sum |rab - a_c*b_c| (abs half), packed f16 ----
  const int m  = bid - NCOLB;
  const int bt = m & 3;
  const int at = (m >> 2) & 3;
  const int s  = (m >> 4) & 7;
  const int cz = m >> 7;                    // 0..CSPLIT-1
  const int a0 = at * TILE;
  const int b0 = bt * TILE;
  const int c0 = cz * CT;                   // exactly one CT-chunk per block

  const int ta = tid & 15;    // a cols: a0 + ta*8 + {0..7}
  const int tb = tid >> 4;    // b cols: b0 + tb*8 + {0..7}

  const _Float16* Ph = P + (size_t)s * N * N;

  // ---- issue ALL global loads first (staging 4 + rab 8), writes later ----
  const int su   = tid & 127;
  const int sh   = tid >> 7;
  const int sisB = su >> 6;
  const int sp   = su & 63;                 // pair index within tile
  const int srow = (sisB ? b0 : a0) + 2 * sp;
  const _Float16* s0row = Ph + (size_t)srow * N + c0 + sh * 16;
  const _Float16* s1row = s0row + N;
  uint4 q0  = ((const uint4*)s0row)[0];
  uint4 q1  = ((const uint4*)s0row)[1];
  uint4 r0v = ((const uint4*)s1row)[0];
  uint4 r1v = ((const uint4*)s1row)[1];

  // rab tile: 8 consecutive b's per a -> one dwordx4 per x. Loads issued here,
  // BEFORE the ds_writes below, so they ride out the staging phase in flight.
  unsigned rabw[8][4];
#pragma unroll
  for (int x = 0; x < 8; ++x) {
    int ga = a0 + ta * 8 + x;
    uint4 q = *(const uint4*)(Ph + (size_t)ga * N + b0 + tb * 8);
    rabw[x][0] = q.x; rabw[x][1] = q.y; rabw[x][2] = q.z; rabw[x][3] = q.w;
  }

  // ---- staging writes: transpose ROW-PAIR x 16 c into LDS column pair ----
  // (ds_write waits vmcnt(8): staging loads done, rab still outstanding)
  {
    _Float16* dst = sisB ? &tB[sh * 16][2 * sp] : &tA[sh * 16][2 * sp];
    unsigned int w0[8] = {q0.x, q0.y, q0.z, q0.w, q1.x, q1.y, q1.z, q1.w};
    unsigned int w1[8] = {r0v.x, r0v.y, r0v.z, r0v.w, r1v.x, r1v.y, r1v.z, r1v.w};
#pragma unroll
    for (int k = 0; k < 8; ++k) {
      unsigned int lo = (w1[k] << 16) | (w0[k] & 0xFFFFu);       // c = 2k
      unsigned int hi = (w1[k] & 0xFFFF0000u) | (w0[k] >> 16);   // c = 2k+1
      *(unsigned int*)(dst + (size_t)(2 * k) * LSTR)     = lo;
      *(unsigned int*)(dst + (size_t)(2 * k + 1) * LSTR) = hi;
    }
  }

  // ---- ANTI-REMAT PIN: make rab values opaque -> must stay in VGPRs ----
#pragma unroll
  for (int x = 0; x < 8; ++x) {
#pragma unroll
    for (int yp = 0; yp < 4; ++yp) {
      asm volatile("" : "+v"(rabw[x][yp]));
    }
  }

  half2_t rab2[8][4];
#pragma unroll
  for (int x = 0; x < 8; ++x) {
#pragma unroll
    for (int yp = 0; yp < 4; ++yp) rab2[x][yp] = u2h(rabw[x][yp]);
  }

  float acc[8];
#pragma unroll
  for (int x = 0; x < 8; ++x) acc[x] = 0.0f;

  const half2_t kOne = {(_Float16)1.0f, (_Float16)1.0f};

  __syncthreads();

#pragma unroll 4
  for (int c = 0; c < CT; ++c) {
    uint4 ua = *(const uint4*)&tA[c][ta * 8];   // 8 a-vals (b128, 2-way free)
    uint4 ub = *(const uint4*)&tB[c][tb * 8];   // 8 b-vals (16-lane broadcast)
    half2_t av[4] = {u2h(ua.x), u2h(ua.y), u2h(ua.z), u2h(ua.w)};
    half2_t bv[4] = {u2h(ub.x), u2h(ub.y), u2h(ub.z), u2h(ub.w)};
#pragma unroll
    for (int x = 0; x < 8; ++x) {
      _Float16 as = (x & 1) ? av[x >> 1].y : av[x >> 1].x;
      half2_t asp = {as, as};
      float a_ = acc[x];
#pragma unroll
      for (int yp = 0; yp < 4; ++yp) {
        half2_t t2 = rab2[x][yp] - asp * bv[yp];     // v_pk_fma_f16 (neg)
        half2_t p2 = u2h(h2u(t2) & 0x7FFF7FFFu);     // packed |t|
        a_ = fdot2_(p2, kOne, a_);                   // f32 accumulate
      }
      acc[x] = a_;
    }
  }

  float tsum = 0.0f;
#pragma unroll
  for (int x = 0; x < 8; ++x) tsum += acc[x];

  for (int off = 32; off > 0; off >>= 1) tsum += __shfl_down(tsum, off, 64);

  const int wid = tid >> 6;
  if ((tid & 63) == 0) wsum[wid] = tsum;
  __syncthreads();
  if (tid == 0)
    atomicAdd(out, (wsum[0] + wsum[1] + wsum[2] + wsum[3]) * SCALE);
}

// ---------------- f32 fallback (no workspace): R4 structure ----------------
#define FCT    64
#define FSTR   132
#define FCSPL  4
#define FNCOLB 16

__global__ __launch_bounds__(256, 2) void work_f32_fallback(const float* __restrict__ logits,
                                                            const int* __restrict__ masks,
                                                            float* __restrict__ out) {
  __shared__ __align__(16) float tA[FCT][FSTR];
  __shared__ __align__(16) float tB[FCT][FSTR];
  __shared__ float wsum[4];

  const int tid = threadIdx.x;
  const int bid = blockIdx.x;

  if (bid < FNCOLB) {
    const int s    = bid >> 1;
    const int half = bid & 1;
    const int c    = half * 256 + tid;
    const int bb   = s >> 2;
    const int r    = s & 3;
    const int* mrow = masks + bb * N;
    float mc = (mrow[c] > 0) ? 1.0f : 0.0f;
    float sum = 0.0f;
#pragma unroll 4
    for (int a = 0; a < N; ++a) {
      float ma = (mrow[a] > 0) ? 1.0f : 0.0f;
      size_t idx = ((size_t)(bb * N + a) * N + c) * RNUM + r;
      sum += sigmoidf_(logits[idx]) * ma * mc;
    }
    float v = sum * ((float)N - sum);
    for (int off = 32; off > 0; off >>= 1) v += __shfl_down(v, off, 64);
    const int wid = tid >> 6;
    if ((tid & 63) == 0) wsum[wid] = v;
    __syncthreads();
    if (tid == 0)
      atomicAdd(out, (wsum[0] + wsum[1] + wsum[2] + wsum[3]) * SCALE);
    return;
  }

  const int m  = bid - FNCOLB;
  const int bt = m & 3;
  const int at = (m >> 2) & 3;
  const int s  = (m >> 4) & 7;
  const int cz = m >> 7;
  const int a0 = at * TILE;
  const int b0 = bt * TILE;
  const int bb = s >> 2;
  const int r  = s & 3;
  const int cbeg = cz * (N / FCSPL);
  const int cend = cbeg + (N / FCSPL);

  const int ta = tid & 15;
  const int tb = tid >> 4;
  const int* mrow = masks + bb * N;

  float rab[8][8];
#pragma unroll
  for (int x = 0; x < 8; ++x) {
    int ra = a0 + ((x >> 2) << 6) + ta * 4 + (x & 3);
    float ma = (mrow[ra] > 0) ? 1.0f : 0.0f;
#pragma unroll
    for (int y = 0; y < 8; ++y) {
      int cb = b0 + ((y >> 2) << 6) + tb * 4 + (y & 3);
      float mb = (mrow[cb] > 0) ? 1.0f : 0.0f;
      size_t idx = ((size_t)(bb * N + ra) * N + cb) * RNUM + r;
      rab[x][y] = sigmoidf_(logits[idx]) * ma * mb;
    }
  }

  float acc[8][2];
#pragma unroll
  for (int x = 0; x < 8; ++x) { acc[x][0] = 0.0f; acc[x][1] = 0.0f; }

  for (int c0 = cbeg; c0 < cend; c0 += FCT) {
    __syncthreads();
#pragma unroll
    for (int it = 0; it < 32; ++it) {
      int e = it * 256 + tid;
      int c = e & 63;
      int i = e >> 6;
      int pc = ((((i >> 2) ^ ((c >> 2) & 31)) & 31) << 2) | (i & 3);
      float mc = (mrow[c0 + c] > 0) ? 1.0f : 0.0f;
      {
        float mi = (mrow[a0 + i] > 0) ? 1.0f : 0.0f;
        size_t idx = ((size_t)(bb * N + a0 + i) * N + (c0 + c)) * RNUM + r;
        tA[c][pc] = sigmoidf_(logits[idx]) * mi * mc;
      }
      {
        float mi = (mrow[b0 + i] > 0) ? 1.0f : 0.0f;
        size_t idx = ((size_t)(bb * N + b0 + i) * N + (c0 + c)) * RNUM + r;
        tB[c][pc] = sigmoidf_(logits[idx]) * mi * mc;
      }
    }
    __syncthreads();

#pragma unroll 2
    for (int cg = 0; cg < FCT / 4; ++cg) {
      const float* pa = &tA[cg * 4][((ta ^ cg) & 31) << 2];
      const float* pb = &tB[cg * 4][((tb ^ cg) & 31) << 2];
#pragma unroll
      for (int dc = 0; dc < 4; ++dc) {
        float4 a0v = *(const float4*)(pa + dc * FSTR);
        float4 a1v = *(const float4*)(pa + dc * FSTR + 64);
        float4 b0v = *(const float4*)(pb + dc * FSTR);
        float4 b1v = *(const float4*)(pb + dc * FSTR + 64);
        float avv[8] = {a0v.x, a0v.y, a0v.z, a0v.w, a1v.x, a1v.y, a1v.z, a1v.w};
        float bvv[8] = {b0v.x, b0v.y, b0v.z, b0v.w, b1v.x, b1v.y, b1v.z, b1v.w};
#pragma unroll
        for (int x = 0; x < 8; ++x) {
#pragma unroll
          for (int y = 0; y < 4; ++y)
            acc[x][0] += fabsf(fmaf(-avv[x], bvv[y], rab[x][y]));
#pragma unroll
          for (int y = 4; y < 8; ++y)
            acc[x][1] += fabsf(fmaf(-avv[x], bvv[y], rab[x][y]));
        }
      }
    }
  }

  float tsum = 0.0f;
#pragma unroll
  for (int x = 0; x < 8; ++x) tsum += acc[x][0] + acc[x][1];
  for (int off = 32; off > 0; off >>= 1) tsum += __shfl_down(tsum, off, 64);
  const int wid = tid >> 6;
  if ((tid & 63) == 0) wsum[wid] = tsum;
  __syncthreads();
  if (tid == 0)
    atomicAdd(out, (wsum[0] + wsum[1] + wsum[2] + wsum[3]) * SCALE);
}

extern "C" void kernel_launch(void* const* d_in, const int* in_sizes, int n_in,
                              void* d_out, int out_size, void* d_ws, size_t ws_size,
                              hipStream_t stream) {
  const float* logits = (const float*)d_in[0];
  const int*   masks  = (const int*)d_in[1];
  float*       out    = (float*)d_out;

  const size_t P_BYTES = (size_t)NSLICE * N * N * sizeof(_Float16);  // 4 MB

  if (ws_size >= P_BYTES) {
    _Float16* P = (_Float16*)d_ws;
    prep_f16_kernel<<<(BNUM * N * N / 4) / 256, 256, 0, stream>>>(logits, masks, P, out);
    const int nblocks = NCOLB + 4 * 4 * NSLICE * CSPLIT;  // 16 + 2048
    work_f16_kernel<<<nblocks, 256, 0, stream>>>(P, out);
  } else {
    zero_out_kernel<<<1, 1, 0, stream>>>(out);
    const int nblocks = FNCOLB + 4 * 4 * NSLICE * FCSPL;  // 16 + 512
    work_f32_fallback<<<nblocks, 256, 0, stream>>>(logits, masks, out);
  }
}